// Round 12
// baseline (188.516 us; speedup 1.0000x reference)
//
#include <hip/hip_runtime.h>

#define D 128
#define MAXN 0.996f            // (1 - BALL_EPS) / sqrt(c), c = 1
#define MINN 1e-15f
#define ARTANH_MAX (1.0f - 1e-7f)
#define MAX_NORM 1e6f

typedef unsigned int uint;
typedef unsigned short ushort;
typedef __bf16 bf16x8 __attribute__((ext_vector_type(8)));
typedef float f32x4 __attribute__((ext_vector_type(4)));

__device__ __forceinline__ float quad_sum(float v) {   // sum lanes l, l^16, l^32, l^48
    v += __shfl_xor(v, 16, 64);
    v += __shfl_xor(v, 32, 64);
    return v;
}

__device__ __forceinline__ float half_sum32(float v) { // reduce within each 32-lane half
    v += __shfl_xor(v, 16, 64);
    v += __shfl_xor(v, 8, 64);
    v += __shfl_xor(v, 4, 64);
    v += __shfl_xor(v, 2, 64);
    v += __shfl_xor(v, 1, 64);
    return v;
}

__device__ __forceinline__ float artanh_clip(float x) {
    x = fminf(fmaxf(x, -ARTANH_MAX), ARTANH_MAX);
    return 0.5f * logf((1.0f + x) / (1.0f - x));
}

__device__ __forceinline__ ushort f2bf(float f) {   // RNE, finite inputs
    uint u = __float_as_uint(f);
    return (ushort)((u + 0x7fffu + ((u >> 16) & 1u)) >> 16);
}

__device__ __forceinline__ uint pk2(float a, float b) {
    return (uint)f2bf(a) | ((uint)f2bf(b) << 16);
}

// ---- W fp32 -> bf16 A-frag swizzle (first 2048 threads) + cnt/done zeroing ----
__global__ __launch_bounds__(256)
void wconv_kernel(const float* __restrict__ W, uint4* __restrict__ WF,
                  int4* __restrict__ cnt4, int n4, int* __restrict__ done)
{
    int idx = blockIdx.x * 256 + threadIdx.x;
    if (idx < 2048) {
        int l = idx & 63, rest = idx >> 6;
        int t = rest & 7, ks = rest >> 3;
        int lr = l & 15, kg = l >> 4;
        const float* wrow = W + (size_t)(t * 16 + lr) * D + ks * 32 + kg * 4;
        float4 lo = *(const float4*)(wrow);
        float4 hi = *(const float4*)(wrow + 16);
        WF[idx] = make_uint4(pk2(lo.x, lo.y), pk2(lo.z, lo.w),
                             pk2(hi.x, hi.y), pk2(hi.z, hi.w));
    }
    if (idx == 0) *done = 0;
    for (int z = idx; z < n4; z += gridDim.x * 256)
        cnt4[z] = make_int4(0, 0, 0, 0);
}

// ---- MFMA GEMM + fused HypLinear ----
__global__ __launch_bounds__(128)
void gemm_mfma_kernel(const float* __restrict__ X, const uint4* __restrict__ WF,
                      const float* __restrict__ bias, ushort* __restrict__ XT, int N)
{
    const int wid = threadIdx.x >> 6;
    const int l   = threadIdx.x & 63;
    const int m0  = (blockIdx.x * 2 + wid) * 16;
    if (m0 >= N) return;
    const int lr = l & 15;          // X row within tile == D col j
    const int kg = l >> 4;          // k-group
    const int row = m0 + lr;
    const int rowc = row < N ? row : N - 1;

    const float* xp = X + (size_t)rowc * D + kg * 4;
    bf16x8 bfr[4];
    float xsq = 0.f;
#pragma unroll
    for (int ks = 0; ks < 4; ++ks) {
        float4 v0 = *(const float4*)(xp + ks * 32);
        float4 v1 = *(const float4*)(xp + ks * 32 + 16);
        xsq += v0.x*v0.x + v0.y*v0.y + v0.z*v0.z + v0.w*v0.w
             + v1.x*v1.x + v1.y*v1.y + v1.z*v1.z + v1.w*v1.w;
        uint4 bq = make_uint4(pk2(v0.x, v0.y), pk2(v0.z, v0.w),
                              pk2(v1.x, v1.y), pk2(v1.z, v1.w));
        bfr[ks] = __builtin_bit_cast(bf16x8, bq);
    }
    xsq = quad_sum(xsq);            // full ||x_row||^2, row = m0+lr

    f32x4 acc[8];
#pragma unroll
    for (int t = 0; t < 8; ++t) acc[t] = (f32x4){0.f, 0.f, 0.f, 0.f};
#pragma unroll
    for (int ks = 0; ks < 4; ++ks) {
        uint4 wv[8];
#pragma unroll
        for (int t = 0; t < 8; ++t) wv[t] = WF[(ks * 8 + t) * 64 + l];
#pragma unroll
        for (int t = 0; t < 8; ++t)
            acc[t] = __builtin_amdgcn_mfma_f32_16x16x32_bf16(
                __builtin_bit_cast(bf16x8, wv[t]), bfr[ks], acc[t], 0, 0, 0);
    }

    float4 bb[8];
    float bsq = 0.f;
#pragma unroll
    for (int t = 0; t < 8; ++t) {
        bb[t] = *(const float4*)(bias + t * 16 + kg * 4);
        bsq += bb[t].x*bb[t].x + bb[t].y*bb[t].y + bb[t].z*bb[t].z + bb[t].w*bb[t].w;
    }
    bsq = quad_sum(bsq);
    float bn  = fmaxf(sqrtf(bsq), MINN);
    float bt  = tanhf(bn);
    float bps = (bt > MAXN) ? MAXN / fmaxf(bt, MINN) : 1.0f;
    float bsc = bt / bn * bps;      // b_hyp = bsc * bias
    float bhn = fminf(fmaxf(bt * bps, MINN), MAXN);
    float y2  = bhn * bhn;

    float sacc = 0.f, sab = 0.f;
#pragma unroll
    for (int t = 0; t < 8; ++t) {
        sacc += acc[t][0]*acc[t][0] + acc[t][1]*acc[t][1] + acc[t][2]*acc[t][2] + acc[t][3]*acc[t][3];
        sab  += acc[t][0]*bb[t].x + acc[t][1]*bb[t].y + acc[t][2]*bb[t].z + acc[t][3]*bb[t].w;
    }
    sacc = quad_sum(sacc);
    sab  = quad_sum(sab);

    float xn  = fmaxf(sqrtf(xsq), MINN);
    float mxn = fmaxf(sqrtf(sacc), MINN);
    float t1  = tanhf(mxn / xn * artanh_clip(xn));    // ||res||
    float s1  = t1 / mxn;
    float ps1 = (t1 > MAXN) ? MAXN / fmaxf(t1, MINN) : 1.0f;
    float s1p = s1 * ps1;
    float rn  = fminf(fmaxf(t1, MINN), MAXN);
    float x2  = rn * rn;
    float mxb = bsc * sab;
    float xy  = s1p * mxb;
    float ca  = 1.0f + 2.0f * xy + y2;
    float cb  = 1.0f - x2;
    float den = fmaxf(1.0f + 2.0f * xy + x2 * y2, MINN);
    float alpha = ca * s1p / den;
    float beta  = cb / den;
    float hn2 = alpha * alpha * sacc + 2.0f * alpha * beta * mxb + beta * beta * y2;
    float hn  = fmaxf(sqrtf(hn2), MINN);
    float ps2 = (hn > MAXN) ? MAXN / hn : 1.0f;
    float hnc = fmaxf(fminf(hn, MAXN), MINN);
    float ls  = artanh_clip(hnc) / hnc;
    float F   = ls * ps2;
    float A = F * alpha, Bc = F * beta * bsc;

    if (row < N) {
        ushort* op = XT + (size_t)row * D + kg * 4;
#pragma unroll
        for (int t = 0; t < 8; ++t) {
            uint2 o = make_uint2(pk2(A * acc[t][0] + Bc * bb[t].x, A * acc[t][1] + Bc * bb[t].y),
                                 pk2(A * acc[t][2] + Bc * bb[t].z, A * acc[t][3] + Bc * bb[t].w));
            *(uint2*)(op + t * 16) = o;
        }
    }
}

// ---------------- CSR build ----------------
__global__ __launch_bounds__(256)
void hist_kernel(const int* __restrict__ erow, int* __restrict__ cnt,
                 int* __restrict__ rank, int E)
{
    int e4 = blockIdx.x * 256 + threadIdx.x;
    int E4 = E >> 2;
    if (e4 < E4) {
        int4 r = ((const int4*)erow)[e4];
        int4 k;
        k.x = atomicAdd(&cnt[r.x], 1);
        k.y = atomicAdd(&cnt[r.y], 1);
        k.z = atomicAdd(&cnt[r.z], 1);
        k.w = atomicAdd(&cnt[r.w], 1);
        ((int4*)rank)[e4] = k;
    }
    if (e4 == 0) {
        for (int i = E4 * 4; i < E; ++i) rank[i] = atomicAdd(&cnt[erow[i]], 1);
    }
}

// ---- scan1 + fused scan2 (last-block pattern) ----
__global__ __launch_bounds__(256)
void scan1_kernel(const int* __restrict__ cnt, int* __restrict__ offs,
                  int* __restrict__ bsum, int* __restrict__ done, int N, int nb)
{
    __shared__ int wsum[4];
    __shared__ int islast;
    int t = threadIdx.x;
    int base = blockIdx.x * 1024 + t * 4;
    int v[4];
#pragma unroll
    for (int j = 0; j < 4; ++j) v[j] = (base + j < N) ? cnt[base + j] : 0;
    int tt = v[0] + v[1] + v[2] + v[3];
    int incl = tt;
#pragma unroll
    for (int o = 1; o < 64; o <<= 1) {
        int n = __shfl_up(incl, o, 64);
        if ((t & 63) >= o) incl += n;
    }
    if ((t & 63) == 63) wsum[t >> 6] = incl;
    __syncthreads();
    int wbase = 0;
    for (int w = 0; w < (t >> 6); ++w) wbase += wsum[w];
    int ex = wbase + incl - tt;
#pragma unroll
    for (int j = 0; j < 4; ++j) {
        if (base + j < N) offs[base + j] = ex;
        ex += v[j];
    }
    if (t == 255) bsum[blockIdx.x] = wbase + incl;
    __threadfence();
    if (t == 255) islast = (atomicAdd(done, 1) == nb - 1);
    __syncthreads();
    if (islast) {
        __threadfence();
        if (t < 64) {
            int bv = (t < nb) ? bsum[t] : 0;
            int incl2 = bv;
#pragma unroll
            for (int o = 1; o < 64; o <<= 1) {
                int n = __shfl_up(incl2, o, 64);
                if (t >= o) incl2 += n;
            }
            if (t < nb) bsum[t] = incl2 - bv;
        }
    }
}

// atomic-free fill (x4): p = offs[row]+bsum[chunk]+rank; 4B edge (col16|val-bf16)
__global__ __launch_bounds__(256)
void fill_kernel(const int* __restrict__ erow, const int* __restrict__ ecol,
                 const float* __restrict__ adj, const int* __restrict__ rank,
                 const int* __restrict__ offs, const int* __restrict__ bsum,
                 uint* __restrict__ bpack, int E)
{
    int e4 = blockIdx.x * 256 + threadIdx.x;
    int E4 = E >> 2;
    if (e4 < E4) {
        int4   r = ((const int4*)erow)[e4];
        int4   c = ((const int4*)ecol)[e4];
        float4 a = ((const float4*)adj)[e4];
        int4   k = ((const int4*)rank)[e4];
        bpack[offs[r.x] + bsum[r.x >> 10] + k.x] = ((uint)c.x << 16) | (uint)f2bf(a.x);
        bpack[offs[r.y] + bsum[r.y >> 10] + k.y] = ((uint)c.y << 16) | (uint)f2bf(a.y);
        bpack[offs[r.z] + bsum[r.z >> 10] + k.z] = ((uint)c.z << 16) | (uint)f2bf(a.z);
        bpack[offs[r.w] + bsum[r.w >> 10] + k.w] = ((uint)c.w << 16) | (uint)f2bf(a.w);
    }
    if (e4 == 0) {
        for (int i = E4 * 4; i < E; ++i) {
            int r = erow[i];
            bpack[offs[r] + bsum[r >> 10] + rank[i]] = ((uint)ecol[i] << 16) | (uint)f2bf(adj[i]);
        }
    }
}

// ------- gather: single 32-edge predicated chunk, all loads in one latency window -------
// hl = lane&31 owns cols 4hl..4hl+3; hi = lane>>5 selects edge parity.
// Masked edges (idx >= end): q=0 -> weight 0, gather row 0 (L1-resident, free).
__global__ __launch_bounds__(256)
void gather_kernel(const ushort* __restrict__ XT, const uint* __restrict__ bpack,
                   const int* __restrict__ offs, const int* __restrict__ bsum,
                   const int* __restrict__ cnt, float* __restrict__ OUT, int N)
{
    int row = blockIdx.x * 4 + (threadIdx.x >> 6);
    int lane = threadIdx.x & 63;
    if (row >= N) return;
    int start = offs[row] + bsum[row >> 10];
    int end = start + cnt[row];
    const uint2* xt2 = (const uint2*)XT;   // row stride = 32 uint2 (4 bf16 cols each)
    const int hl = lane & 31;
    const int hi = lane >> 5;
    float acc[4][4] = {{0.f}};

    for (int base = start; base < end; base += 32) {
        uint4 qq[8];
#pragma unroll
        for (int j = 0; j < 8; ++j)
            qq[j] = *(const uint4*)(bpack + base + j * 4);   // padded past E by 32
        uint q[16];
#pragma unroll
        for (int j = 0; j < 8; ++j) {
            q[2 * j]     = hi ? qq[j].y : qq[j].x;
            q[2 * j + 1] = hi ? qq[j].w : qq[j].z;
        }
#pragma unroll
        for (int k = 0; k < 16; ++k)
            if (base + 2 * k + hi >= end) q[k] = 0;          // mask: weight 0, row 0
        uint2 u[16];
#pragma unroll
        for (int k = 0; k < 16; ++k)
            u[k] = xt2[(size_t)(q[k] >> 16) * 32 + hl];      // 16 independent loads
#pragma unroll
        for (int k = 0; k < 16; ++k) {
            float v = __uint_as_float(q[k] << 16);
            acc[k & 3][0] += v * __uint_as_float(u[k].x << 16);
            acc[k & 3][1] += v * __uint_as_float(u[k].x & 0xffff0000u);
            acc[k & 3][2] += v * __uint_as_float(u[k].y << 16);
            acc[k & 3][3] += v * __uint_as_float(u[k].y & 0xffff0000u);
        }
    }
    float c0 = (acc[0][0] + acc[1][0]) + (acc[2][0] + acc[3][0]);
    float c1 = (acc[0][1] + acc[1][1]) + (acc[2][1] + acc[3][1]);
    float c2 = (acc[0][2] + acc[1][2]) + (acc[2][2] + acc[3][2]);
    float c3 = (acc[0][3] + acc[1][3]) + (acc[2][3] + acc[3][3]);
    c0 += __shfl_xor(c0, 32, 64);
    c1 += __shfl_xor(c1, 32, 64);
    c2 += __shfl_xor(c2, 32, 64);
    c3 += __shfl_xor(c3, 32, 64);
    c0 = fminf(c0, MAX_NORM); c1 = fminf(c1, MAX_NORM);
    c2 = fminf(c2, MAX_NORM); c3 = fminf(c3, MAX_NORM);
    // expmap0 + proj + logmap0 analytic: ||expmap0(t)|| = tanh(||t||)
    float nt = fmaxf(sqrtf(half_sum32(c0*c0 + c1*c1 + c2*c2 + c3*c3)), MINN);
    float th = tanhf(nt);
    float es = th / nt;
    float pf = (th > MAXN) ? MAXN / th : 1.0f;
    float hnc = fmaxf(fminf(th, MAXN), MINN);
    float ls = artanh_clip(hnc) / hnc;
    float su = ls * pf * es;
    float u0 = fminf(fmaxf(su * c0, 0.0f), MAX_NORM);
    float u1 = fminf(fmaxf(su * c1, 0.0f), MAX_NORM);
    float u2 = fminf(fmaxf(su * c2, 0.0f), MAX_NORM);
    float u3 = fminf(fmaxf(su * c3, 0.0f), MAX_NORM);
    float un = fmaxf(sqrtf(half_sum32(u0*u0 + u1*u1 + u2*u2 + u3*u3)), MINN);
    float os = tanhf(un) / un;
    if (hi == 0)
        *(float4*)(OUT + (size_t)row * D + hl * 4) =
            make_float4(os * u0, os * u1, os * u2, os * u3);
}

extern "C" void kernel_launch(void* const* d_in, const int* in_sizes, int n_in,
                              void* d_out, int out_size, void* d_ws, size_t ws_size,
                              hipStream_t stream)
{
    const float* x    = (const float*)d_in[0];
    const float* adj  = (const float*)d_in[1];
    const float* W    = (const float*)d_in[2];
    const float* bias = (const float*)d_in[3];
    const int*   erow = (const int*)d_in[4];
    const int*   ecol = (const int*)d_in[5];
    float* out = (float*)d_out;
    const int N = in_sizes[0] / D;   // 50000 (< 65536: col fits 16 bits in bpack)
    const int E = in_sizes[1];

    char* p = (char*)d_ws;
    size_t off = 0;
    auto alloc = [&](size_t bytes) {
        char* r = p + off;
        off = (off + bytes + 255) & ~(size_t)255;
        return r;
    };
    ushort* xt  = (ushort*)alloc((size_t)N * D * sizeof(ushort));
    uint4*  wf  = (uint4*) alloc(2048 * sizeof(uint4));   // swizzled W frags
    int*   cnt  = (int*)  alloc(((size_t)N + 4) * sizeof(int));
    int*   offs = (int*)  alloc((size_t)N * sizeof(int));
    int*   bsum = (int*)  alloc(256 * sizeof(int));
    int*   done = (int*)  alloc(256);
    int*   rank = (int*)  alloc((size_t)E * sizeof(int));
    uint*  bpack= (uint*) alloc(((size_t)E + 32) * sizeof(uint));  // +32 pad for chunk overread
    (void)ws_size;

    int n4 = (N + 3) >> 2;
    wconv_kernel<<<64, 256, 0, stream>>>(W, wf, (int4*)cnt, n4, done);
    gemm_mfma_kernel<<<(N + 31) / 32, 128, 0, stream>>>(x, wf, bias, xt, N);
    int E4 = E >> 2;
    hist_kernel<<<(E4 + 255) / 256, 256, 0, stream>>>(erow, cnt, rank, E);
    int nb = (N + 1023) / 1024;   // 49 for N=50000, must be <= 64
    scan1_kernel<<<nb, 256, 0, stream>>>(cnt, offs, bsum, done, N, nb);
    fill_kernel<<<(E4 + 255) / 256, 256, 0, stream>>>(erow, ecol, adj, rank, offs, bsum, bpack, E);
    gather_kernel<<<(N + 3) / 4, 256, 0, stream>>>(xt, bpack, offs, bsum, cnt, out, N);
}

// Round 13
// 117.243 us; speedup vs baseline: 1.6079x; 1.6079x over previous
//
#include <hip/hip_runtime.h>

#define D 128
#define MAXN 0.996f            // (1 - BALL_EPS) / sqrt(c), c = 1
#define MINN 1e-15f
#define ARTANH_MAX (1.0f - 1e-7f)
#define MAX_NORM 1e6f

typedef unsigned int uint;
typedef unsigned short ushort;
typedef __bf16 bf16x8 __attribute__((ext_vector_type(8)));
typedef float f32x4 __attribute__((ext_vector_type(4)));

__device__ __forceinline__ float wave_sum(float v) {
#pragma unroll
    for (int o = 32; o > 0; o >>= 1) v += __shfl_xor(v, o, 64);
    return v;
}

__device__ __forceinline__ float quad_sum(float v) {   // sum lanes l, l^16, l^32, l^48
    v += __shfl_xor(v, 16, 64);
    v += __shfl_xor(v, 32, 64);
    return v;
}

__device__ __forceinline__ float artanh_clip(float x) {
    x = fminf(fmaxf(x, -ARTANH_MAX), ARTANH_MAX);
    return 0.5f * logf((1.0f + x) / (1.0f - x));
}

__device__ __forceinline__ ushort f2bf(float f) {   // RNE, finite inputs
    uint u = __float_as_uint(f);
    return (ushort)((u + 0x7fffu + ((u >> 16) & 1u)) >> 16);
}

__device__ __forceinline__ uint pk2(float a, float b) {
    return (uint)f2bf(a) | ((uint)f2bf(b) << 16);
}

// ---- W fp32 -> bf16 A-frag swizzle (first 2048 threads) + cnt zeroing ----
// WF[(ks*8 + t)*64 + l] = 16B frag: W[t*16+lr][ks*32+kg*4 ..+3 , +16..+19], lr=l&15, kg=l>>4
__global__ __launch_bounds__(256)
void wconv_kernel(const float* __restrict__ W, uint4* __restrict__ WF,
                  int4* __restrict__ cnt4, int n4)
{
    int idx = blockIdx.x * 256 + threadIdx.x;
    if (idx < 2048) {
        int l = idx & 63, rest = idx >> 6;
        int t = rest & 7, ks = rest >> 3;
        int lr = l & 15, kg = l >> 4;
        const float* wrow = W + (size_t)(t * 16 + lr) * D + ks * 32 + kg * 4;
        float4 lo = *(const float4*)(wrow);
        float4 hi = *(const float4*)(wrow + 16);
        WF[idx] = make_uint4(pk2(lo.x, lo.y), pk2(lo.z, lo.w),
                             pk2(hi.x, hi.y), pk2(hi.z, hi.w));
    }
    // zero cnt (replaces rocclr fillBuffer launch)
    for (int z = idx; z < n4; z += gridDim.x * 256)
        cnt4[z] = make_int4(0, 0, 0, 0);
}

// ---- MFMA GEMM + fused HypLinear: xt[m][:] = A_m*(x_m @ W^T) + B_m*b_hyp, bf16 out ----
// Per wave: 16 X-rows. A-frag = pre-swizzled W (coalesced uint4), B-frag = X rows (cvt).
// C/D map: Dcol j = lane&15 (X row), Drow i = (lane>>4)*4 + reg  [verified R5].
__global__ __launch_bounds__(128)
void gemm_mfma_kernel(const float* __restrict__ X, const uint4* __restrict__ WF,
                      const float* __restrict__ bias, ushort* __restrict__ XT, int N)
{
    const int wid = threadIdx.x >> 6;
    const int l   = threadIdx.x & 63;
    const int m0  = (blockIdx.x * 2 + wid) * 16;
    if (m0 >= N) return;
    const int lr = l & 15;          // X row within tile == D col j
    const int kg = l >> 4;          // k-group
    const int row = m0 + lr;
    const int rowc = row < N ? row : N - 1;

    const float* xp = X + (size_t)rowc * D + kg * 4;
    bf16x8 bfr[4];
    float xsq = 0.f;
#pragma unroll
    for (int ks = 0; ks < 4; ++ks) {
        float4 v0 = *(const float4*)(xp + ks * 32);
        float4 v1 = *(const float4*)(xp + ks * 32 + 16);
        xsq += v0.x*v0.x + v0.y*v0.y + v0.z*v0.z + v0.w*v0.w
             + v1.x*v1.x + v1.y*v1.y + v1.z*v1.z + v1.w*v1.w;
        uint4 bq = make_uint4(pk2(v0.x, v0.y), pk2(v0.z, v0.w),
                              pk2(v1.x, v1.y), pk2(v1.z, v1.w));
        bfr[ks] = __builtin_bit_cast(bf16x8, bq);
    }
    xsq = quad_sum(xsq);            // full ||x_row||^2, row = m0+lr

    f32x4 acc[8];
#pragma unroll
    for (int t = 0; t < 8; ++t) acc[t] = (f32x4){0.f, 0.f, 0.f, 0.f};
#pragma unroll
    for (int ks = 0; ks < 4; ++ks) {
        uint4 wv[8];
#pragma unroll
        for (int t = 0; t < 8; ++t) wv[t] = WF[(ks * 8 + t) * 64 + l];
#pragma unroll
        for (int t = 0; t < 8; ++t)
            acc[t] = __builtin_amdgcn_mfma_f32_16x16x32_bf16(
                __builtin_bit_cast(bf16x8, wv[t]), bfr[ks], acc[t], 0, 0, 0);
    }

    float4 bb[8];
    float bsq = 0.f;
#pragma unroll
    for (int t = 0; t < 8; ++t) {
        bb[t] = *(const float4*)(bias + t * 16 + kg * 4);
        bsq += bb[t].x*bb[t].x + bb[t].y*bb[t].y + bb[t].z*bb[t].z + bb[t].w*bb[t].w;
    }
    bsq = quad_sum(bsq);            // ||bias||^2 (replicated)
    float bn  = fmaxf(sqrtf(bsq), MINN);
    float bt  = tanhf(bn);
    float bps = (bt > MAXN) ? MAXN / fmaxf(bt, MINN) : 1.0f;
    float bsc = bt / bn * bps;      // b_hyp = bsc * bias
    float bhn = fminf(fmaxf(bt * bps, MINN), MAXN);
    float y2  = bhn * bhn;

    float sacc = 0.f, sab = 0.f;
#pragma unroll
    for (int t = 0; t < 8; ++t) {
        sacc += acc[t][0]*acc[t][0] + acc[t][1]*acc[t][1] + acc[t][2]*acc[t][2] + acc[t][3]*acc[t][3];
        sab  += acc[t][0]*bb[t].x + acc[t][1]*bb[t].y + acc[t][2]*bb[t].z + acc[t][3]*bb[t].w;
    }
    sacc = quad_sum(sacc);
    sab  = quad_sum(sab);

    float xn  = fmaxf(sqrtf(xsq), MINN);
    float mxn = fmaxf(sqrtf(sacc), MINN);
    float t1  = tanhf(mxn / xn * artanh_clip(xn));    // ||res||
    float s1  = t1 / mxn;
    float ps1 = (t1 > MAXN) ? MAXN / fmaxf(t1, MINN) : 1.0f;
    float s1p = s1 * ps1;
    float rn  = fminf(fmaxf(t1, MINN), MAXN);
    float x2  = rn * rn;
    float mxb = bsc * sab;
    float xy  = s1p * mxb;
    float ca  = 1.0f + 2.0f * xy + y2;
    float cb  = 1.0f - x2;
    float den = fmaxf(1.0f + 2.0f * xy + x2 * y2, MINN);
    float alpha = ca * s1p / den;
    float beta  = cb / den;
    float hn2 = alpha * alpha * sacc + 2.0f * alpha * beta * mxb + beta * beta * y2;
    float hn  = fmaxf(sqrtf(hn2), MINN);
    float ps2 = (hn > MAXN) ? MAXN / hn : 1.0f;
    float hnc = fmaxf(fminf(hn, MAXN), MINN);
    float ls  = artanh_clip(hnc) / hnc;
    float F   = ls * ps2;
    float A = F * alpha, Bc = F * beta * bsc;

    if (row < N) {
        ushort* op = XT + (size_t)row * D + kg * 4;
#pragma unroll
        for (int t = 0; t < 8; ++t) {
            uint2 o = make_uint2(pk2(A * acc[t][0] + Bc * bb[t].x, A * acc[t][1] + Bc * bb[t].y),
                                 pk2(A * acc[t][2] + Bc * bb[t].z, A * acc[t][3] + Bc * bb[t].w));
            *(uint2*)(op + t * 16) = o;
        }
    }
}

// ---------------- CSR build ----------------
// hist (x4 vectorized): records each edge's arrival rank within its row
__global__ __launch_bounds__(256)
void hist_kernel(const int* __restrict__ erow, int* __restrict__ cnt,
                 int* __restrict__ rank, int E)
{
    int e4 = blockIdx.x * 256 + threadIdx.x;
    int E4 = E >> 2;
    if (e4 < E4) {
        int4 r = ((const int4*)erow)[e4];
        int4 k;
        k.x = atomicAdd(&cnt[r.x], 1);
        k.y = atomicAdd(&cnt[r.y], 1);
        k.z = atomicAdd(&cnt[r.z], 1);
        k.w = atomicAdd(&cnt[r.w], 1);
        ((int4*)rank)[e4] = k;
    }
    if (e4 == 0) {
        for (int i = E4 * 4; i < E; ++i) rank[i] = atomicAdd(&cnt[erow[i]], 1);
    }
}

// block-level partial exclusive scan: 1024 elems/block (256 thr x 4)
__global__ __launch_bounds__(256)
void scan1_kernel(const int* __restrict__ cnt, int* __restrict__ offs,
                  int* __restrict__ bsum, int N)
{
    __shared__ int wsum[4];
    int t = threadIdx.x;
    int base = blockIdx.x * 1024 + t * 4;
    int v[4];
#pragma unroll
    for (int j = 0; j < 4; ++j) v[j] = (base + j < N) ? cnt[base + j] : 0;
    int tt = v[0] + v[1] + v[2] + v[3];
    int incl = tt;
#pragma unroll
    for (int o = 1; o < 64; o <<= 1) {
        int n = __shfl_up(incl, o, 64);
        if ((t & 63) >= o) incl += n;
    }
    if ((t & 63) == 63) wsum[t >> 6] = incl;
    __syncthreads();
    int wbase = 0;
    for (int w = 0; w < (t >> 6); ++w) wbase += wsum[w];
    int ex = wbase + incl - tt;
#pragma unroll
    for (int j = 0; j < 4; ++j) {
        if (base + j < N) offs[base + j] = ex;
        ex += v[j];
    }
    if (t == 255) bsum[blockIdx.x] = wbase + incl;
}

__global__ __launch_bounds__(64)
void scan2_kernel(int* __restrict__ bsum, int nb)
{
    int l = threadIdx.x;
    int v = (l < nb) ? bsum[l] : 0;
    int incl = v;
#pragma unroll
    for (int o = 1; o < 64; o <<= 1) {
        int n = __shfl_up(incl, o, 64);
        if (l >= o) incl += n;
    }
    if (l < nb) bsum[l] = incl - v;
}

// atomic-free fill (x4 vectorized): p = offs[row]+bsum[chunk]+rank; 4B edge (col16|val-bf16)
__global__ __launch_bounds__(256)
void fill_kernel(const int* __restrict__ erow, const int* __restrict__ ecol,
                 const float* __restrict__ adj, const int* __restrict__ rank,
                 const int* __restrict__ offs, const int* __restrict__ bsum,
                 uint* __restrict__ bpack, int E)
{
    int e4 = blockIdx.x * 256 + threadIdx.x;
    int E4 = E >> 2;
    if (e4 < E4) {
        int4   r = ((const int4*)erow)[e4];
        int4   c = ((const int4*)ecol)[e4];
        float4 a = ((const float4*)adj)[e4];
        int4   k = ((const int4*)rank)[e4];
        bpack[offs[r.x] + bsum[r.x >> 10] + k.x] = ((uint)c.x << 16) | (uint)f2bf(a.x);
        bpack[offs[r.y] + bsum[r.y >> 10] + k.y] = ((uint)c.y << 16) | (uint)f2bf(a.y);
        bpack[offs[r.z] + bsum[r.z >> 10] + k.z] = ((uint)c.z << 16) | (uint)f2bf(a.z);
        bpack[offs[r.w] + bsum[r.w >> 10] + k.w] = ((uint)c.w << 16) | (uint)f2bf(a.w);
    }
    if (e4 == 0) {
        for (int i = E4 * 4; i < E; ++i) {
            int r = erow[i];
            bpack[offs[r] + bsum[r >> 10] + rank[i]] = ((uint)ecol[i] << 16) | (uint)f2bf(adj[i]);
        }
    }
}

// ------- gather (bf16 rows, 4B edges, 8-deep ILP) + fused HypAct tail (2 wave_sums) -------
__global__ __launch_bounds__(256)
void gather_kernel(const ushort* __restrict__ XT, const uint* __restrict__ bpack,
                   const int* __restrict__ offs, const int* __restrict__ bsum,
                   const int* __restrict__ cnt, float* __restrict__ OUT, int N)
{
    int row = blockIdx.x * 4 + (threadIdx.x >> 6);
    int lane = threadIdx.x & 63;
    if (row >= N) return;
    int start = offs[row] + bsum[row >> 10];
    int end = start + cnt[row];
    const uint* xtw = (const uint*)XT;   // 1 uint = 2 bf16 cols per lane
    float ax[8] = {0.f, 0.f, 0.f, 0.f, 0.f, 0.f, 0.f, 0.f};
    float ay[8] = {0.f, 0.f, 0.f, 0.f, 0.f, 0.f, 0.f, 0.f};
    int i = start;
    for (; i + 7 < end; i += 8) {
        uint4 qa = *(const uint4*)(bpack + i);       // wave-uniform 16B loads
        uint4 qb = *(const uint4*)(bpack + i + 4);
        uint q[8] = {qa.x, qa.y, qa.z, qa.w, qb.x, qb.y, qb.z, qb.w};
#pragma unroll
        for (int j = 0; j < 8; ++j) {
            uint u = xtw[(size_t)(q[j] >> 16) * 64 + lane];
            float v = __uint_as_float(q[j] << 16);
            ax[j] += v * __uint_as_float(u << 16);
            ay[j] += v * __uint_as_float(u & 0xffff0000u);
        }
    }
    for (; i + 3 < end; i += 4) {
        uint4 qa = *(const uint4*)(bpack + i);
        uint q[4] = {qa.x, qa.y, qa.z, qa.w};
#pragma unroll
        for (int j = 0; j < 4; ++j) {
            uint u = xtw[(size_t)(q[j] >> 16) * 64 + lane];
            float v = __uint_as_float(q[j] << 16);
            ax[j] += v * __uint_as_float(u << 16);
            ay[j] += v * __uint_as_float(u & 0xffff0000u);
        }
    }
    for (; i < end; ++i) {
        uint q = bpack[i];
        float v = __uint_as_float(q << 16);
        uint u = xtw[(size_t)(q >> 16) * 64 + lane];
        ax[0] += v * __uint_as_float(u << 16);
        ay[0] += v * __uint_as_float(u & 0xffff0000u);
    }
    float tx = ((ax[0] + ax[1]) + (ax[2] + ax[3])) + ((ax[4] + ax[5]) + (ax[6] + ax[7]));
    float ty = ((ay[0] + ay[1]) + (ay[2] + ay[3])) + ((ay[4] + ay[5]) + (ay[6] + ay[7]));
    tx = fminf(tx, MAX_NORM);
    ty = fminf(ty, MAX_NORM);
    // expmap0 + proj + logmap0 with analytic norms: ||expmap0(t)|| = tanh(||t||)
    float nt = fmaxf(sqrtf(wave_sum(tx * tx + ty * ty)), MINN);
    float th = tanhf(nt);
    float es = th / nt;                               // expmap0 scale
    float pf = (th > MAXN) ? MAXN / th : 1.0f;        // proj scale
    float hnc = fmaxf(fminf(th, MAXN), MINN);         // ||h|| after proj
    float ls = artanh_clip(hnc) / hnc;                // logmap0 scale
    float su = ls * pf * es;
    float u0 = fminf(fmaxf(su * tx, 0.0f), MAX_NORM); // relu + clamp
    float u1 = fminf(fmaxf(su * ty, 0.0f), MAX_NORM);
    // final expmap0
    float un = fmaxf(sqrtf(wave_sum(u0 * u0 + u1 * u1)), MINN);
    float os = tanhf(un) / un;
    float2 o; o.x = os * u0; o.y = os * u1;
    ((float2*)(OUT + (size_t)row * D))[lane] = o;
}

extern "C" void kernel_launch(void* const* d_in, const int* in_sizes, int n_in,
                              void* d_out, int out_size, void* d_ws, size_t ws_size,
                              hipStream_t stream)
{
    const float* x    = (const float*)d_in[0];
    const float* adj  = (const float*)d_in[1];
    const float* W    = (const float*)d_in[2];
    const float* bias = (const float*)d_in[3];
    const int*   erow = (const int*)d_in[4];
    const int*   ecol = (const int*)d_in[5];
    float* out = (float*)d_out;
    const int N = in_sizes[0] / D;   // 50000 (< 65536: col fits 16 bits in bpack)
    const int E = in_sizes[1];

    char* p = (char*)d_ws;
    size_t off = 0;
    auto alloc = [&](size_t bytes) {
        char* r = p + off;
        off = (off + bytes + 255) & ~(size_t)255;
        return r;
    };
    ushort* xt  = (ushort*)alloc((size_t)N * D * sizeof(ushort));
    uint4*  wf  = (uint4*) alloc(2048 * sizeof(uint4));   // swizzled W frags
    int*   cnt  = (int*)  alloc(((size_t)N + 4) * sizeof(int));
    int*   offs = (int*)  alloc((size_t)N * sizeof(int));
    int*   bsum = (int*)  alloc(256 * sizeof(int));
    int*   rank = (int*)  alloc((size_t)E * sizeof(int));
    uint*  bpack= (uint*) alloc((size_t)E * sizeof(uint));
    (void)ws_size;

    int n4 = (N + 3) >> 2;
    wconv_kernel<<<64, 256, 0, stream>>>(W, wf, (int4*)cnt, n4);
    gemm_mfma_kernel<<<(N + 31) / 32, 128, 0, stream>>>(x, wf, bias, xt, N);
    int E4 = E >> 2;
    hist_kernel<<<(E4 + 255) / 256, 256, 0, stream>>>(erow, cnt, rank, E);
    int nb = (N + 1023) / 1024;   // 49 for N=50000, must be <= 64
    scan1_kernel<<<nb, 256, 0, stream>>>(cnt, offs, bsum, N);
    scan2_kernel<<<1, 64, 0, stream>>>(bsum, nb);
    fill_kernel<<<(E4 + 255) / 256, 256, 0, stream>>>(erow, ecol, adj, rank, offs, bsum, bpack, E);
    gather_kernel<<<(N + 3) / 4, 256, 0, stream>>>(xt, bpack, offs, bsum, cnt, out, N);
}

// Round 15
// 116.917 us; speedup vs baseline: 1.6124x; 1.0028x over previous
//
#include <hip/hip_runtime.h>

#define D 128
#define MAXN 0.996f            // (1 - BALL_EPS) / sqrt(c), c = 1
#define MINN 1e-15f
#define ARTANH_MAX (1.0f - 1e-7f)
#define MAX_NORM 1e6f

typedef unsigned int uint;
typedef unsigned short ushort;
typedef __bf16 bf16x8 __attribute__((ext_vector_type(8)));
typedef float f32x4 __attribute__((ext_vector_type(4)));

__device__ __forceinline__ float wave_sum(float v) {
#pragma unroll
    for (int o = 32; o > 0; o >>= 1) v += __shfl_xor(v, o, 64);
    return v;
}

__device__ __forceinline__ float quad_sum(float v) {   // sum lanes l, l^16, l^32, l^48
    v += __shfl_xor(v, 16, 64);
    v += __shfl_xor(v, 32, 64);
    return v;
}

__device__ __forceinline__ float artanh_clip(float x) {
    x = fminf(fmaxf(x, -ARTANH_MAX), ARTANH_MAX);
    return 0.5f * logf((1.0f + x) / (1.0f - x));
}

__device__ __forceinline__ ushort f2bf(float f) {   // RNE, finite inputs
    uint u = __float_as_uint(f);
    return (ushort)((u + 0x7fffu + ((u >> 16) & 1u)) >> 16);
}

__device__ __forceinline__ uint pk2(float a, float b) {
    return (uint)f2bf(a) | ((uint)f2bf(b) << 16);
}

// ---- W fp32 -> bf16 A-frag swizzle (first 2048 threads) + cnt zeroing ----
// WF[(ks*8 + t)*64 + l] = 16B frag: W[t*16+lr][ks*32+kg*4 ..+3 , +16..+19], lr=l&15, kg=l>>4
__global__ __launch_bounds__(256)
void wconv_kernel(const float* __restrict__ W, uint4* __restrict__ WF,
                  int4* __restrict__ cnt4, int n4)
{
    int idx = blockIdx.x * 256 + threadIdx.x;
    if (idx < 2048) {
        int l = idx & 63, rest = idx >> 6;
        int t = rest & 7, ks = rest >> 3;
        int lr = l & 15, kg = l >> 4;
        const float* wrow = W + (size_t)(t * 16 + lr) * D + ks * 32 + kg * 4;
        float4 lo = *(const float4*)(wrow);
        float4 hi = *(const float4*)(wrow + 16);
        WF[idx] = make_uint4(pk2(lo.x, lo.y), pk2(lo.z, lo.w),
                             pk2(hi.x, hi.y), pk2(hi.z, hi.w));
    }
    // zero cnt (replaces rocclr fillBuffer launch)
    for (int z = idx; z < n4; z += gridDim.x * 256)
        cnt4[z] = make_int4(0, 0, 0, 0);
}

// ---- MFMA GEMM + fused HypLinear: xt[m][:] = A_m*(x_m @ W^T) + B_m*b_hyp, bf16 out ----
// Per wave: 16 X-rows. A-frag = pre-swizzled W (coalesced uint4), B-frag = X rows (cvt).
// C/D map: Dcol j = lane&15 (X row), Drow i = (lane>>4)*4 + reg  [verified R5].
__global__ __launch_bounds__(128)
void gemm_mfma_kernel(const float* __restrict__ X, const uint4* __restrict__ WF,
                      const float* __restrict__ bias, ushort* __restrict__ XT, int N)
{
    const int wid = threadIdx.x >> 6;
    const int l   = threadIdx.x & 63;
    const int m0  = (blockIdx.x * 2 + wid) * 16;
    if (m0 >= N) return;
    const int lr = l & 15;          // X row within tile == D col j
    const int kg = l >> 4;          // k-group
    const int row = m0 + lr;
    const int rowc = row < N ? row : N - 1;

    const float* xp = X + (size_t)rowc * D + kg * 4;
    bf16x8 bfr[4];
    float xsq = 0.f;
#pragma unroll
    for (int ks = 0; ks < 4; ++ks) {
        float4 v0 = *(const float4*)(xp + ks * 32);
        float4 v1 = *(const float4*)(xp + ks * 32 + 16);
        xsq += v0.x*v0.x + v0.y*v0.y + v0.z*v0.z + v0.w*v0.w
             + v1.x*v1.x + v1.y*v1.y + v1.z*v1.z + v1.w*v1.w;
        uint4 bq = make_uint4(pk2(v0.x, v0.y), pk2(v0.z, v0.w),
                              pk2(v1.x, v1.y), pk2(v1.z, v1.w));
        bfr[ks] = __builtin_bit_cast(bf16x8, bq);
    }
    xsq = quad_sum(xsq);            // full ||x_row||^2, row = m0+lr

    f32x4 acc[8];
#pragma unroll
    for (int t = 0; t < 8; ++t) acc[t] = (f32x4){0.f, 0.f, 0.f, 0.f};
#pragma unroll
    for (int ks = 0; ks < 4; ++ks) {
        uint4 wv[8];
#pragma unroll
        for (int t = 0; t < 8; ++t) wv[t] = WF[(ks * 8 + t) * 64 + l];
#pragma unroll
        for (int t = 0; t < 8; ++t)
            acc[t] = __builtin_amdgcn_mfma_f32_16x16x32_bf16(
                __builtin_bit_cast(bf16x8, wv[t]), bfr[ks], acc[t], 0, 0, 0);
    }

    float4 bb[8];
    float bsq = 0.f;
#pragma unroll
    for (int t = 0; t < 8; ++t) {
        bb[t] = *(const float4*)(bias + t * 16 + kg * 4);
        bsq += bb[t].x*bb[t].x + bb[t].y*bb[t].y + bb[t].z*bb[t].z + bb[t].w*bb[t].w;
    }
    bsq = quad_sum(bsq);            // ||bias||^2 (replicated)
    float bn  = fmaxf(sqrtf(bsq), MINN);
    float bt  = tanhf(bn);
    float bps = (bt > MAXN) ? MAXN / fmaxf(bt, MINN) : 1.0f;
    float bsc = bt / bn * bps;      // b_hyp = bsc * bias
    float bhn = fminf(fmaxf(bt * bps, MINN), MAXN);
    float y2  = bhn * bhn;

    float sacc = 0.f, sab = 0.f;
#pragma unroll
    for (int t = 0; t < 8; ++t) {
        sacc += acc[t][0]*acc[t][0] + acc[t][1]*acc[t][1] + acc[t][2]*acc[t][2] + acc[t][3]*acc[t][3];
        sab  += acc[t][0]*bb[t].x + acc[t][1]*bb[t].y + acc[t][2]*bb[t].z + acc[t][3]*bb[t].w;
    }
    sacc = quad_sum(sacc);
    sab  = quad_sum(sab);

    float xn  = fmaxf(sqrtf(xsq), MINN);
    float mxn = fmaxf(sqrtf(sacc), MINN);
    float t1  = tanhf(mxn / xn * artanh_clip(xn));    // ||res||
    float s1  = t1 / mxn;
    float ps1 = (t1 > MAXN) ? MAXN / fmaxf(t1, MINN) : 1.0f;
    float s1p = s1 * ps1;
    float rn  = fminf(fmaxf(t1, MINN), MAXN);
    float x2  = rn * rn;
    float mxb = bsc * sab;
    float xy  = s1p * mxb;
    float ca  = 1.0f + 2.0f * xy + y2;
    float cb  = 1.0f - x2;
    float den = fmaxf(1.0f + 2.0f * xy + x2 * y2, MINN);
    float alpha = ca * s1p / den;
    float beta  = cb / den;
    float hn2 = alpha * alpha * sacc + 2.0f * alpha * beta * mxb + beta * beta * y2;
    float hn  = fmaxf(sqrtf(hn2), MINN);
    float ps2 = (hn > MAXN) ? MAXN / hn : 1.0f;
    float hnc = fmaxf(fminf(hn, MAXN), MINN);
    float ls  = artanh_clip(hnc) / hnc;
    float F   = ls * ps2;
    float A = F * alpha, Bc = F * beta * bsc;

    if (row < N) {
        ushort* op = XT + (size_t)row * D + kg * 4;
#pragma unroll
        for (int t = 0; t < 8; ++t) {
            uint2 o = make_uint2(pk2(A * acc[t][0] + Bc * bb[t].x, A * acc[t][1] + Bc * bb[t].y),
                                 pk2(A * acc[t][2] + Bc * bb[t].z, A * acc[t][3] + Bc * bb[t].w));
            *(uint2*)(op + t * 16) = o;
        }
    }
}

// ---------------- CSR build ----------------
// hist: 1 edge/thread — returning atomics need max TLP (x4 vectorization was 47us, R13)
__global__ __launch_bounds__(256)
void hist_kernel(const int* __restrict__ erow, int* __restrict__ cnt,
                 int* __restrict__ rank, int E)
{
    int e = blockIdx.x * 256 + threadIdx.x;
    if (e < E) rank[e] = atomicAdd(&cnt[erow[e]], 1);
}

// block-level partial exclusive scan: 1024 elems/block (256 thr x 4)
__global__ __launch_bounds__(256)
void scan1_kernel(const int* __restrict__ cnt, int* __restrict__ offs,
                  int* __restrict__ bsum, int N)
{
    __shared__ int wsum[4];
    int t = threadIdx.x;
    int base = blockIdx.x * 1024 + t * 4;
    int v[4];
#pragma unroll
    for (int j = 0; j < 4; ++j) v[j] = (base + j < N) ? cnt[base + j] : 0;
    int tt = v[0] + v[1] + v[2] + v[3];
    int incl = tt;
#pragma unroll
    for (int o = 1; o < 64; o <<= 1) {
        int n = __shfl_up(incl, o, 64);
        if ((t & 63) >= o) incl += n;
    }
    if ((t & 63) == 63) wsum[t >> 6] = incl;
    __syncthreads();
    int wbase = 0;
    for (int w = 0; w < (t >> 6); ++w) wbase += wsum[w];
    int ex = wbase + incl - tt;
#pragma unroll
    for (int j = 0; j < 4; ++j) {
        if (base + j < N) offs[base + j] = ex;
        ex += v[j];
    }
    if (t == 255) bsum[blockIdx.x] = wbase + incl;
}

__global__ __launch_bounds__(64)
void scan2_kernel(int* __restrict__ bsum, int nb)
{
    int l = threadIdx.x;
    int v = (l < nb) ? bsum[l] : 0;
    int incl = v;
#pragma unroll
    for (int o = 1; o < 64; o <<= 1) {
        int n = __shfl_up(incl, o, 64);
        if (l >= o) incl += n;
    }
    if (l < nb) bsum[l] = incl - v;
}

// atomic-free fill (x4 vectorized): p = offs[row]+bsum[chunk]+rank; 4B edge (col16|val-bf16)
__global__ __launch_bounds__(256)
void fill_kernel(const int* __restrict__ erow, const int* __restrict__ ecol,
                 const float* __restrict__ adj, const int* __restrict__ rank,
                 const int* __restrict__ offs, const int* __restrict__ bsum,
                 uint* __restrict__ bpack, int E)
{
    int e4 = blockIdx.x * 256 + threadIdx.x;
    int E4 = E >> 2;
    if (e4 < E4) {
        int4   r = ((const int4*)erow)[e4];
        int4   c = ((const int4*)ecol)[e4];
        float4 a = ((const float4*)adj)[e4];
        int4   k = ((const int4*)rank)[e4];
        bpack[offs[r.x] + bsum[r.x >> 10] + k.x] = ((uint)c.x << 16) | (uint)f2bf(a.x);
        bpack[offs[r.y] + bsum[r.y >> 10] + k.y] = ((uint)c.y << 16) | (uint)f2bf(a.y);
        bpack[offs[r.z] + bsum[r.z >> 10] + k.z] = ((uint)c.z << 16) | (uint)f2bf(a.z);
        bpack[offs[r.w] + bsum[r.w >> 10] + k.w] = ((uint)c.w << 16) | (uint)f2bf(a.w);
    }
    if (e4 == 0) {
        for (int i = E4 * 4; i < E; ++i) {
            int r = erow[i];
            bpack[offs[r] + bsum[r >> 10] + rank[i]] = ((uint)ecol[i] << 16) | (uint)f2bf(adj[i]);
        }
    }
}

// ------- gather (bf16 rows, 4B edges, 8-deep ILP) + fused HypAct tail (2 wave_sums) -------
__global__ __launch_bounds__(256)
void gather_kernel(const ushort* __restrict__ XT, const uint* __restrict__ bpack,
                   const int* __restrict__ offs, const int* __restrict__ bsum,
                   const int* __restrict__ cnt, float* __restrict__ OUT, int N)
{
    int row = blockIdx.x * 4 + (threadIdx.x >> 6);
    int lane = threadIdx.x & 63;
    if (row >= N) return;
    int start = offs[row] + bsum[row >> 10];
    int end = start + cnt[row];
    const uint* xtw = (const uint*)XT;   // 1 uint = 2 bf16 cols per lane
    float ax[8] = {0.f, 0.f, 0.f, 0.f, 0.f, 0.f, 0.f, 0.f};
    float ay[8] = {0.f, 0.f, 0.f, 0.f, 0.f, 0.f, 0.f, 0.f};
    int i = start;
    for (; i + 7 < end; i += 8) {
        uint4 qa = *(const uint4*)(bpack + i);       // wave-uniform 16B loads
        uint4 qb = *(const uint4*)(bpack + i + 4);
        uint q[8] = {qa.x, qa.y, qa.z, qa.w, qb.x, qb.y, qb.z, qb.w};
#pragma unroll
        for (int j = 0; j < 8; ++j) {
            uint u = xtw[(size_t)(q[j] >> 16) * 64 + lane];
            float v = __uint_as_float(q[j] << 16);
            ax[j] += v * __uint_as_float(u << 16);
            ay[j] += v * __uint_as_float(u & 0xffff0000u);
        }
    }
    for (; i + 3 < end; i += 4) {
        uint4 qa = *(const uint4*)(bpack + i);
        uint q[4] = {qa.x, qa.y, qa.z, qa.w};
#pragma unroll
        for (int j = 0; j < 4; ++j) {
            uint u = xtw[(size_t)(q[j] >> 16) * 64 + lane];
            float v = __uint_as_float(q[j] << 16);
            ax[j] += v * __uint_as_float(u << 16);
            ay[j] += v * __uint_as_float(u & 0xffff0000u);
        }
    }
    for (; i < end; ++i) {
        uint q = bpack[i];
        float v = __uint_as_float(q << 16);
        uint u = xtw[(size_t)(q >> 16) * 64 + lane];
        ax[0] += v * __uint_as_float(u << 16);
        ay[0] += v * __uint_as_float(u & 0xffff0000u);
    }
    float tx = ((ax[0] + ax[1]) + (ax[2] + ax[3])) + ((ax[4] + ax[5]) + (ax[6] + ax[7]));
    float ty = ((ay[0] + ay[1]) + (ay[2] + ay[3])) + ((ay[4] + ay[5]) + (ay[6] + ay[7]));
    tx = fminf(tx, MAX_NORM);
    ty = fminf(ty, MAX_NORM);
    // expmap0 + proj + logmap0 with analytic norms: ||expmap0(t)|| = tanh(||t||)
    float nt = fmaxf(sqrtf(wave_sum(tx * tx + ty * ty)), MINN);
    float th = tanhf(nt);
    float es = th / nt;                               // expmap0 scale
    float pf = (th > MAXN) ? MAXN / th : 1.0f;        // proj scale
    float hnc = fmaxf(fminf(th, MAXN), MINN);         // ||h|| after proj
    float ls = artanh_clip(hnc) / hnc;                // logmap0 scale
    float su = ls * pf * es;
    float u0 = fminf(fmaxf(su * tx, 0.0f), MAX_NORM); // relu + clamp
    float u1 = fminf(fmaxf(su * ty, 0.0f), MAX_NORM);
    // final expmap0
    float un = fmaxf(sqrtf(wave_sum(u0 * u0 + u1 * u1)), MINN);
    float os = tanhf(un) / un;
    float2 o; o.x = os * u0; o.y = os * u1;
    ((float2*)(OUT + (size_t)row * D))[lane] = o;
}

extern "C" void kernel_launch(void* const* d_in, const int* in_sizes, int n_in,
                              void* d_out, int out_size, void* d_ws, size_t ws_size,
                              hipStream_t stream)
{
    const float* x    = (const float*)d_in[0];
    const float* adj  = (const float*)d_in[1];
    const float* W    = (const float*)d_in[2];
    const float* bias = (const float*)d_in[3];
    const int*   erow = (const int*)d_in[4];
    const int*   ecol = (const int*)d_in[5];
    float* out = (float*)d_out;
    const int N = in_sizes[0] / D;   // 50000 (< 65536: col fits 16 bits in bpack)
    const int E = in_sizes[1];

    char* p = (char*)d_ws;
    size_t off = 0;
    auto alloc = [&](size_t bytes) {
        char* r = p + off;
        off = (off + bytes + 255) & ~(size_t)255;
        return r;
    };
    ushort* xt  = (ushort*)alloc((size_t)N * D * sizeof(ushort));
    uint4*  wf  = (uint4*) alloc(2048 * sizeof(uint4));   // swizzled W frags
    int*   cnt  = (int*)  alloc(((size_t)N + 4) * sizeof(int));
    int*   offs = (int*)  alloc((size_t)N * sizeof(int));
    int*   bsum = (int*)  alloc(256 * sizeof(int));
    int*   rank = (int*)  alloc((size_t)E * sizeof(int));
    uint*  bpack= (uint*) alloc((size_t)E * sizeof(uint));
    (void)ws_size;

    int n4 = (N + 3) >> 2;
    wconv_kernel<<<64, 256, 0, stream>>>(W, wf, (int4*)cnt, n4);
    gemm_mfma_kernel<<<(N + 31) / 32, 128, 0, stream>>>(x, wf, bias, xt, N);
    hist_kernel<<<(E + 255) / 256, 256, 0, stream>>>(erow, cnt, rank, E);
    int nb = (N + 1023) / 1024;   // 49 for N=50000, must be <= 64
    scan1_kernel<<<nb, 256, 0, stream>>>(cnt, offs, bsum, N);
    scan2_kernel<<<1, 64, 0, stream>>>(bsum, nb);
    int fb = ((E >> 2) + 255) / 256;
    fill_kernel<<<fb, 256, 0, stream>>>(erow, ecol, adj, rank, offs, bsum, bpack, E);
    gather_kernel<<<(N + 3) / 4, 256, 0, stream>>>(xt, bpack, offs, bsum, cnt, out, N);
}